// Round 2
// baseline (46.737 us; speedup 1.0000x reference)
//
#include <hip/hip_runtime.h>

// ParallelLatticeModel: B=131072 rows, D=16 features, 4 lattices of 4 dims,
// E=24 ensemble columns, K=16 calibration keypoints, 16 corners per lattice.
//
// v2: 2 threads per row, split across WAVES (wave-uniform e-group so lattice
// kernel reads stay scalar s_loads). 4096 waves -> 4 waves/SIMD for s_load
// latency hiding; per-wave k1/k2 scalar traffic halved. Layer-2 uses
// precomputed corner diffs (8 fewer muls per column). Dual accumulators break
// the 16-deep fma chain in layer-1 dots.

namespace {
constexpr int kB      = 131072;
constexpr int kD      = 16;
constexpr int kL1     = 4;
constexpr int kE      = 24;
constexpr int kK      = 16;
constexpr int kNV     = 16;
constexpr int kNSeg   = 15;    // K-1 segments per calibrator
constexpr int kTPR    = 2;     // threads (waves) per row
constexpr int kEPT    = kE / kTPR;  // 12 columns per thread
constexpr int kThreads = 256;  // 4 waves: {eg0,eg1} x {rowblk0,rowblk1}
constexpr int kRowsPerBlock = 128;
// workspace layout (floats): [0,240) dx, [240,480) slope, [480,672) dk2
constexpr int kTblDx    = 0;
constexpr int kTblSlope = kD * kNSeg;        // 240
constexpr int kTblDk2   = 2 * kD * kNSeg;    // 480
}

__global__ void prep_tables(const float* __restrict__ cal_kp,
                            const float* __restrict__ cal_vals,
                            const float* __restrict__ k2,
                            float* __restrict__ tbl) {
    int idx = blockIdx.x * blockDim.x + threadIdx.x;
    if (idx < kD * kNSeg) {
        int d = idx / kNSeg;
        int k = idx - d * kNSeg;
        float kp0 = cal_kp[d * kK + k];
        float kp1 = cal_kp[d * kK + k + 1];
        float v0  = cal_vals[d * kK + k];
        float v1  = cal_vals[d * kK + k + 1];
        float dx  = kp1 - kp0;
        float slope = (dx > 0.0f) ? (v1 - v0) / dx : 0.0f;
        tbl[kTblDx + idx]    = dx;
        tbl[kTblSlope + idx] = slope;
    }
    if (idx < kE * 8) {   // layer-2 corner diffs along dim 3 (LSB)
        int e = idx >> 3;
        int j = idx & 7;
        tbl[kTblDk2 + idx] = k2[e * kNV + 2 * j + 1] - k2[e * kNV + 2 * j];
    }
}

__global__ __launch_bounds__(kThreads) void lattice_fwd(
    const float* __restrict__ x,
    const float* __restrict__ cal_kp,
    const float* __restrict__ cal_vals,
    const float* __restrict__ k1,    // [E][L1][NV]
    const float* __restrict__ k2,    // [E][NV]
    const float* __restrict__ tbl,   // dx[240], slope[240], dk2[192]
    float* __restrict__ out)         // [B][E]
{
    const int tid    = threadIdx.x;
    const int wave   = tid >> 6;            // 0..3
    const int lane   = tid & 63;
    const int eg     = wave & 1;            // WAVE-uniform e-group -> s_loads
    const int rowblk = wave >> 1;           // 0 or 1
    const int row    = blockIdx.x * kRowsPerBlock + rowblk * 64 + lane;

    // ---- load input row (64B, aligned, coalesced across lanes) ----
    float xr[kD];
    const float4* xp = reinterpret_cast<const float4*>(x + (size_t)row * kD);
    #pragma unroll
    for (int i = 0; i < kD / 4; ++i) {
        float4 v = xp[i];
        xr[4*i+0] = v.x; xr[4*i+1] = v.y; xr[4*i+2] = v.z; xr[4*i+3] = v.w;
    }

    // ---- piecewise-linear calibration to [0,1] ----
    // interp(x) = v0 + sum_k slope_k * clamp(x - kp_k, 0, dx_k)
    float xc[kD];
    #pragma unroll
    for (int d = 0; d < kD; ++d) {
        float acc = cal_vals[d * kK];                 // uniform -> SGPR
        float xv  = xr[d];
        #pragma unroll
        for (int k = 0; k < kNSeg; ++k) {
            float t = xv - cal_kp[d * kK + k];
            t = fminf(fmaxf(t, 0.0f), tbl[kTblDx + d * kNSeg + k]);   // v_med3
            acc = fmaf(tbl[kTblSlope + d * kNSeg + k], t, acc);
        }
        xc[d] = fminf(fmaxf(acc, 0.0f), 1.0f);        // clip_inputs=True
    }

    // ---- layer-1 multilinear weights, dim 0 = MSB of corner index ----
    float w[kL1][kNV];
    #pragma unroll
    for (int l = 0; l < kL1; ++l) {
        float a = xc[4*l+0], b = xc[4*l+1], c = xc[4*l+2], dd = xc[4*l+3];
        float t2[2] = {1.0f - a, a};
        float t4[4];
        #pragma unroll
        for (int j = 0; j < 2; ++j) { t4[2*j] = t2[j]*(1.0f-b); t4[2*j+1] = t2[j]*b; }
        float t8[8];
        #pragma unroll
        for (int j = 0; j < 4; ++j) { t8[2*j] = t4[j]*(1.0f-c); t8[2*j+1] = t4[j]*c; }
        #pragma unroll
        for (int j = 0; j < 8; ++j) { w[l][2*j] = t8[j]*(1.0f-dd); w[l][2*j+1] = t8[j]*dd; }
    }

    // ---- this wave's 12 ensemble columns ----
    const float* k1e  = k1  + (size_t)eg * kEPT * kL1 * kNV;   // uniform
    const float* k2e  = k2  + (size_t)eg * kEPT * kNV;
    const float* dk2e = tbl + kTblDk2 + eg * kEPT * 8;

    float o[kEPT];
    #pragma unroll
    for (int e = 0; e < kEPT; ++e) {
        float h[kL1];
        #pragma unroll
        for (int l = 0; l < kL1; ++l) {
            const float* kk = k1e + ((e * kL1 + l) * kNV);     // uniform -> s_load
            float acc0 = 0.0f, acc1 = 0.0f;                    // break dep chain
            #pragma unroll
            for (int c = 0; c < 8; ++c) {
                acc0 = fmaf(w[l][c],     kk[c],     acc0);
                acc1 = fmaf(w[l][c + 8], kk[c + 8], acc1);
            }
            float acc = acc0 + acc1;
            h[l] = fminf(fmaxf(acc, 0.0f), 1.0f);              // clip for layer 2
        }
        // layer-2: contract corners LSB-first (dim 3 is LSB)
        const float* kb = k2e  + e * kNV;                      // uniform
        const float* db = dk2e + e * 8;
        float h3 = h[3];
        float v8[8];
        #pragma unroll
        for (int j = 0; j < 8; ++j) v8[j] = fmaf(h3, db[j], kb[2*j]);
        float v4[4];
        #pragma unroll
        for (int j = 0; j < 4; ++j) v4[j] = fmaf(h[2], v8[2*j+1] - v8[2*j], v8[2*j]);
        float v2[2];
        #pragma unroll
        for (int j = 0; j < 2; ++j) v2[j] = fmaf(h[1], v4[2*j+1] - v4[2*j], v4[2*j]);
        o[e] = fmaf(h[0], v2[1] - v2[0], v2[0]);
    }

    // ---- store 12 floats = 3 x float4 (row*96B + eg*48B, 16B aligned) ----
    float4* op = reinterpret_cast<float4*>(out + (size_t)row * kE + eg * kEPT);
    #pragma unroll
    for (int i = 0; i < kEPT / 4; ++i) {
        float4 v;
        v.x = o[4*i+0]; v.y = o[4*i+1]; v.z = o[4*i+2]; v.w = o[4*i+3];
        op[i] = v;
    }
}

extern "C" void kernel_launch(void* const* d_in, const int* in_sizes, int n_in,
                              void* d_out, int out_size, void* d_ws, size_t ws_size,
                              hipStream_t stream) {
    const float* x        = (const float*)d_in[0];
    const float* cal_kp   = (const float*)d_in[1];
    const float* cal_vals = (const float*)d_in[2];
    const float* k1       = (const float*)d_in[3];
    const float* k2       = (const float*)d_in[4];
    float* out = (float*)d_out;
    float* tbl = (float*)d_ws;   // needs 672 floats = 2688 B

    hipLaunchKernelGGL(prep_tables, dim3(1), dim3(kThreads), 0, stream,
                       cal_kp, cal_vals, k2, tbl);
    hipLaunchKernelGGL(lattice_fwd, dim3(kB / kRowsPerBlock), dim3(kThreads), 0, stream,
                       x, cal_kp, cal_vals, k1, k2, tbl, out);
}

// Round 3
// 20.780 us; speedup vs baseline: 2.2492x; 2.2492x over previous
//
#include <hip/hip_runtime.h>

// ParallelLatticeModel v3: MFMA for layer-1, LDS-staged tables, 2 threads/row.
//
// B=131072 rows, D=16 features, 4 lattices x 4 dims (16 corners), E=24 cols,
// K=16 calibration keypoints.
//
// Structure (block = 256 threads = 4 waves, 128 rows):
//   phase 0: stage k1 as fp16 MFMA B-fragments + k2 (fp32) into LDS.
//   phase 1: waves {0,1}/{2,3} handle rows 0-63/64-127; wave parity = feature
//            half (wave-uniform -> calibration tables stay s_loads). Each
//            thread calibrates 8 features, builds 2 lattices' 16 corner
//            weights, writes fp16 A-fragments to LDS.
//   phase 2: per wave: 2 M-tiles x 2 N-tiles x 4 lattices of
//            v_mfma_f32_16x16x16_f16 (K=16 exact). C layout: col=lane&15,
//            row=4*(lane>>4)+reg  => each lane holds h[0..3] for 4 (row,e)
//            pairs in-lane; layer-2 lerp chain on VALU; k2[e] read per-lane
//            from LDS (e = lane&15 matches C col).

typedef _Float16 f16x4 __attribute__((ext_vector_type(4)));
typedef float f32x4 __attribute__((ext_vector_type(4)));

namespace {
constexpr int kD = 16, kE = 24, kK = 16, kNV = 16, kNSeg = 15;
constexpr int kThreads = 256;
constexpr int kRPB = 128;            // rows per block
constexpr int kMT  = kRPB / 16;      // 8 M-tiles per block
constexpr int kK2S = 20;             // sK2 row stride in dwords (bank spread)
// tbl (workspace): [0,240) dx, [240,480) slope
constexpr int kTblDx = 0, kTblSlope = kD * kNSeg;
}

__global__ void prep_tables(const float* __restrict__ cal_kp,
                            const float* __restrict__ cal_vals,
                            float* __restrict__ tbl) {
    int idx = blockIdx.x * blockDim.x + threadIdx.x;
    if (idx < kD * kNSeg) {
        int d = idx / kNSeg;
        int k = idx - d * kNSeg;
        float kp0 = cal_kp[d * kK + k];
        float kp1 = cal_kp[d * kK + k + 1];
        float v0  = cal_vals[d * kK + k];
        float v1  = cal_vals[d * kK + k + 1];
        float dx  = kp1 - kp0;
        float slope = (dx > 0.0f) ? (v1 - v0) / dx : 0.0f;
        tbl[kTblDx + idx]    = dx;
        tbl[kTblSlope + idx] = slope;
    }
}

__global__ __launch_bounds__(kThreads, 4) void lattice_fwd(
    const float* __restrict__ x,
    const float* __restrict__ cal_kp,
    const float* __restrict__ cal_vals,
    const float* __restrict__ k1,    // [E][4][16] f32
    const float* __restrict__ k2,    // [E][16] f32
    const float* __restrict__ tbl,   // dx[240], slope[240]
    float* __restrict__ out)         // [B][E] f32
{
    __shared__ f16x4 sW[kMT * 4 * 64];   // [mtile][lattice][lane]  16 KB
    __shared__ f16x4 sK1[4 * 2 * 64];    // [lattice][ntile][lane]   4 KB
    __shared__ float sK2[32 * kK2S];     // [e][20]                2.5 KB

    const int tid  = threadIdx.x;
    const int lane = tid & 63;
    const int wv   = __builtin_amdgcn_readfirstlane(tid >> 6);   // 0..3, uniform

    // ---------------- phase 0: stage k1 (B-frags) and k2 ----------------
    // B-frag for (lattice l, ntile n): lane holds B[k][col] with
    // col = 16n + (lane&15) = e, k = 4*(lane>>4) + j.
    #pragma unroll
    for (int s0 = 0; s0 < 2; ++s0) {
        int s  = tid + s0 * kThreads;    // slot in [0,512)
        int l  = s >> 7;
        int n  = (s >> 6) & 1;
        int ls = s & 63;
        int e  = n * 16 + (ls & 15);
        int g  = ls >> 4;
        f16x4 v = {(_Float16)0, (_Float16)0, (_Float16)0, (_Float16)0};
        if (e < kE) {
            const float* src = k1 + ((size_t)(e * 4 + l) * kNV + 4 * g);
            v[0] = (_Float16)src[0];
            v[1] = (_Float16)src[1];
            v[2] = (_Float16)src[2];
            v[3] = (_Float16)src[3];
        }
        sK1[s] = v;
    }
    {
        int e = tid >> 3;                // 0..31
        int j = tid & 7;
        if (e < kE) {
            sK2[e * kK2S + j]     = k2[e * kNV + j];
            sK2[e * kK2S + j + 8] = k2[e * kNV + j + 8];
        }
    }

    // ---------------- phase 1: calibrate + weights -> A-frags ----------------
    const int half     = wv & 1;                      // feature half, uniform
    const int rowInBlk = ((wv >> 1) << 6) + lane;     // 0..127
    const size_t row   = (size_t)blockIdx.x * kRPB + rowInBlk;

    float xr[8];
    {
        const f32x4* xp = reinterpret_cast<const f32x4*>(x + row * kD + half * 8);
        f32x4 v0 = xp[0], v1 = xp[1];
        xr[0]=v0[0]; xr[1]=v0[1]; xr[2]=v0[2]; xr[3]=v0[3];
        xr[4]=v1[0]; xr[5]=v1[1]; xr[6]=v1[2]; xr[7]=v1[3];
    }

    // piecewise-linear calibration: v0 + sum_k slope_k * clamp(x-kp_k, 0, dx_k)
    float xc[8];
    #pragma unroll
    for (int i = 0; i < 8; ++i) {
        int d = half * 8 + i;                         // uniform -> s_loads
        float acc = cal_vals[d * kK];
        float xv  = xr[i];
        #pragma unroll
        for (int k = 0; k < kNSeg; ++k) {
            float t = xv - cal_kp[d * kK + k];
            t = fminf(fmaxf(t, 0.0f), tbl[kTblDx + d * kNSeg + k]);
            acc = fmaf(tbl[kTblSlope + d * kNSeg + k], t, acc);
        }
        xc[i] = fminf(fmaxf(acc, 0.0f), 1.0f);        // clip_inputs=True
    }

    // multilinear corner weights for this thread's 2 lattices (dim0 = MSB)
    float wf[2][16];
    #pragma unroll
    for (int li = 0; li < 2; ++li) {
        float a = xc[4*li+0], b = xc[4*li+1], c = xc[4*li+2], d = xc[4*li+3];
        float t2[2] = {1.0f - a, a};
        float t4[4];
        #pragma unroll
        for (int j = 0; j < 2; ++j) { t4[2*j] = t2[j]*(1.0f-b); t4[2*j+1] = t2[j]*b; }
        float t8[8];
        #pragma unroll
        for (int j = 0; j < 4; ++j) { t8[2*j] = t4[j]*(1.0f-c); t8[2*j+1] = t4[j]*c; }
        #pragma unroll
        for (int j = 0; j < 8; ++j) { wf[li][2*j] = t8[j]*(1.0f-d); wf[li][2*j+1] = t8[j]*d; }
    }

    // write A-fragments: slot (m,l,lane') holds w[row=16m+(lane'&15)][l][4*(lane'>>4)..+3]
    {
        int m   = rowInBlk >> 4;
        int r15 = rowInBlk & 15;
        #pragma unroll
        for (int li = 0; li < 2; ++li) {
            int l = half * 2 + li;
            #pragma unroll
            for (int g = 0; g < 4; ++g) {
                f16x4 v;
                v[0] = (_Float16)wf[li][4*g+0];
                v[1] = (_Float16)wf[li][4*g+1];
                v[2] = (_Float16)wf[li][4*g+2];
                v[3] = (_Float16)wf[li][4*g+3];
                sW[(m * 4 + l) * 64 + r15 + 16 * g] = v;
            }
        }
    }

    __syncthreads();

    // ---------------- phase 2: MFMA layer-1 + VALU layer-2 ----------------
    f16x4 af[2][4];                      // this wave's 2 M-tiles x 4 lattices
    #pragma unroll
    for (int mi = 0; mi < 2; ++mi)
        #pragma unroll
        for (int l = 0; l < 4; ++l)
            af[mi][l] = sW[((wv * 2 + mi) * 4 + l) * 64 + lane];

    f16x4 bf[4][2];
    #pragma unroll
    for (int l = 0; l < 4; ++l)
        #pragma unroll
        for (int n = 0; n < 2; ++n)
            bf[l][n] = sK1[(l * 2 + n) * 64 + lane];

    const size_t outRowBase = (size_t)blockIdx.x * kRPB;

    #pragma unroll
    for (int n = 0; n < 2; ++n) {
        const int e = n * 16 + (lane & 15);
        const bool valid = (e < kE);
        float kb[16];
        {
            const f32x4* kp = reinterpret_cast<const f32x4*>(&sK2[e * kK2S]);
            #pragma unroll
            for (int j = 0; j < 4; ++j) {
                f32x4 t = kp[j];
                kb[4*j+0]=t[0]; kb[4*j+1]=t[1]; kb[4*j+2]=t[2]; kb[4*j+3]=t[3];
            }
        }
        float db[8];
        #pragma unroll
        for (int j = 0; j < 8; ++j) db[j] = kb[2*j+1] - kb[2*j];

        #pragma unroll
        for (int mi = 0; mi < 2; ++mi) {
            f32x4 acc[4];
            #pragma unroll
            for (int l = 0; l < 4; ++l)
                acc[l] = __builtin_amdgcn_mfma_f32_16x16x16f16(
                    af[mi][l], bf[l][n], (f32x4){0.f, 0.f, 0.f, 0.f}, 0, 0, 0);

            #pragma unroll
            for (int r = 0; r < 4; ++r) {
                float h0 = fminf(fmaxf(acc[0][r], 0.0f), 1.0f);
                float h1 = fminf(fmaxf(acc[1][r], 0.0f), 1.0f);
                float h2 = fminf(fmaxf(acc[2][r], 0.0f), 1.0f);
                float h3 = fminf(fmaxf(acc[3][r], 0.0f), 1.0f);
                float v8[8];
                #pragma unroll
                for (int j = 0; j < 8; ++j) v8[j] = fmaf(h3, db[j], kb[2*j]);
                float v4[4];
                #pragma unroll
                for (int j = 0; j < 4; ++j) v4[j] = fmaf(h2, v8[2*j+1]-v8[2*j], v8[2*j]);
                float v2[2];
                #pragma unroll
                for (int j = 0; j < 2; ++j) v2[j] = fmaf(h1, v4[2*j+1]-v4[2*j], v4[2*j]);
                float o = fmaf(h0, v2[1]-v2[0], v2[0]);
                if (valid) {
                    size_t orow = outRowBase + (wv * 2 + mi) * 16 + ((lane >> 4) << 2) + r;
                    out[orow * kE + e] = o;
                }
            }
        }
    }
}

extern "C" void kernel_launch(void* const* d_in, const int* in_sizes, int n_in,
                              void* d_out, int out_size, void* d_ws, size_t ws_size,
                              hipStream_t stream) {
    const float* x        = (const float*)d_in[0];
    const float* cal_kp   = (const float*)d_in[1];
    const float* cal_vals = (const float*)d_in[2];
    const float* k1       = (const float*)d_in[3];
    const float* k2       = (const float*)d_in[4];
    float* out = (float*)d_out;
    float* tbl = (float*)d_ws;   // 480 floats

    hipLaunchKernelGGL(prep_tables, dim3(1), dim3(kThreads), 0, stream,
                       cal_kp, cal_vals, tbl);
    hipLaunchKernelGGL(lattice_fwd, dim3(131072 / kRPB), dim3(kThreads), 0, stream,
                       x, cal_kp, cal_vals, k1, k2, tbl, out);
}